// Round 3
// baseline (2923.990 us; speedup 1.0000x reference)
//
#include <hip/hip_runtime.h>
#include <stdint.h>

typedef __bf16 bf16x8 __attribute__((ext_vector_type(8)));
typedef float f32x4 __attribute__((ext_vector_type(4)));

#define BETA 0.25f

__device__ __forceinline__ unsigned short f2bf(float f) {
    __bf16 h = (__bf16)f;
    return __builtin_bit_cast(unsigned short, h);
}
__device__ __forceinline__ float bfu2f(unsigned int u) {
    unsigned int x = (u & 0xffffu) << 16;
    return __builtin_bit_cast(float, x);
}

// ---------------------------------------------------------------------------
// f32 VALU GEMM: O = act(A @ W + bias).  All f32 (argmin-critical path:
// products exact, accumulation-order-only deviation from np ~1e-6).
// Tile 64x64, BK=16; 256 threads, 4x4 outputs/thread.
// ---------------------------------------------------------------------------
template <bool RELU>
__global__ __launch_bounds__(256) void gemm_f32(
    const float* __restrict__ A, const float* __restrict__ W,
    const float* __restrict__ bias, float* __restrict__ O,
    int M, int N, int K)
{
    __shared__ float Asf[16][68];  // [k][m], pad 68 avoids stride-64 conflicts
    __shared__ float Bsf[16][68];  // [k][n]

    const int t = threadIdx.x;
    const int m0 = blockIdx.y * 64, n0 = blockIdx.x * 64;
    const int tx = t & 15, ty = t >> 4;
    float c[4][4] = {};

    const int sm = t >> 2, skc = t & 3;        // A staging: row, k-chunk
    const int bk = t >> 4, bn4 = (t & 15) * 4; // B staging: k-row, n-chunk

    for (int kb = 0; kb < K; kb += 16) {
        float4 av = *(const float4*)(A + (size_t)(m0 + sm) * K + kb + skc * 4);
        float4 bw = *(const float4*)(W + (size_t)(kb + bk) * N + n0 + bn4);

        __syncthreads();
        Asf[skc * 4 + 0][sm] = av.x;
        Asf[skc * 4 + 1][sm] = av.y;
        Asf[skc * 4 + 2][sm] = av.z;
        Asf[skc * 4 + 3][sm] = av.w;
        *(float4*)&Bsf[bk][bn4] = bw;
        __syncthreads();

#pragma unroll
        for (int k = 0; k < 16; ++k) {
            float4 a = *(const float4*)&Asf[k][ty * 4];
            float4 b = *(const float4*)&Bsf[k][tx * 4];
            c[0][0] = fmaf(a.x, b.x, c[0][0]); c[0][1] = fmaf(a.x, b.y, c[0][1]);
            c[0][2] = fmaf(a.x, b.z, c[0][2]); c[0][3] = fmaf(a.x, b.w, c[0][3]);
            c[1][0] = fmaf(a.y, b.x, c[1][0]); c[1][1] = fmaf(a.y, b.y, c[1][1]);
            c[1][2] = fmaf(a.y, b.z, c[1][2]); c[1][3] = fmaf(a.y, b.w, c[1][3]);
            c[2][0] = fmaf(a.z, b.x, c[2][0]); c[2][1] = fmaf(a.z, b.y, c[2][1]);
            c[2][2] = fmaf(a.z, b.z, c[2][2]); c[2][3] = fmaf(a.z, b.w, c[2][3]);
            c[3][0] = fmaf(a.w, b.x, c[3][0]); c[3][1] = fmaf(a.w, b.y, c[3][1]);
            c[3][2] = fmaf(a.w, b.z, c[3][2]); c[3][3] = fmaf(a.w, b.w, c[3][3]);
        }
    }

    float4 bv = *(const float4*)(bias + n0 + tx * 4);
#pragma unroll
    for (int i = 0; i < 4; ++i) {
        int row = m0 + ty * 4 + i;
        float4 o;
        o.x = c[i][0] + bv.x; o.y = c[i][1] + bv.y;
        o.z = c[i][2] + bv.z; o.w = c[i][3] + bv.w;
        if (RELU) {
            o.x = fmaxf(o.x, 0.f); o.y = fmaxf(o.y, 0.f);
            o.z = fmaxf(o.z, 0.f); o.w = fmaxf(o.w, 0.f);
        }
        *(float4*)(O + (size_t)row * N + n0 + tx * 4) = o;
    }
}

// ---------------------------------------------------------------------------
// bf16 MFMA GEMM for the DECODER only (2% output tolerance).  A: f32 or bf16;
// W,bias: f32 (converted to bf16 during staging).  Output bf16 or f32.
// Tile 64x64, BK=32, 4 waves, each 32x32 via 2x2 of 16x16x32 MFMA.
// ---------------------------------------------------------------------------
template <bool AF32, bool RELU, bool OUTF32>
__global__ __launch_bounds__(256) void gemm_mfma(
    const void* __restrict__ Av, const float* __restrict__ W,
    const float* __restrict__ bias, void* __restrict__ Ov,
    int M, int N, int K)
{
    __shared__ unsigned short As[64][40];
    __shared__ unsigned short Bs[64][40];  // Bs[n][k]

    const int t = threadIdx.x;
    const int m0 = blockIdx.y * 64;
    const int n0 = blockIdx.x * 64;
    const int wave = t >> 6, lane = t & 63;
    const int wm = wave & 1, wn = wave >> 1;
    const int l15 = lane & 15, kq = lane >> 4;

    f32x4 acc[2][2] = {};

    const int sm = t >> 2, skc = t & 3;   // A staging
    const int sk = t & 31, sng = t >> 5;  // B staging

    for (int kb = 0; kb < K; kb += 32) {
        uint4 va;
        if (AF32) {
            const float* A = (const float*)Av;
            const float4* p = (const float4*)(A + (size_t)(m0 + sm) * K + kb + skc * 8);
            float4 a0 = p[0], a1 = p[1];
            va.x = (unsigned int)f2bf(a0.x) | ((unsigned int)f2bf(a0.y) << 16);
            va.y = (unsigned int)f2bf(a0.z) | ((unsigned int)f2bf(a0.w) << 16);
            va.z = (unsigned int)f2bf(a1.x) | ((unsigned int)f2bf(a1.y) << 16);
            va.w = (unsigned int)f2bf(a1.z) | ((unsigned int)f2bf(a1.w) << 16);
        } else {
            const unsigned short* A = (const unsigned short*)Av;
            va = *(const uint4*)(A + (size_t)(m0 + sm) * K + kb + skc * 8);
        }
        const float4* wp = (const float4*)(W + (size_t)(kb + sk) * N + n0 + sng * 8);
        float4 w0 = wp[0], w1 = wp[1];
        unsigned short e[8] = {f2bf(w0.x), f2bf(w0.y), f2bf(w0.z), f2bf(w0.w),
                               f2bf(w1.x), f2bf(w1.y), f2bf(w1.z), f2bf(w1.w)};

        __syncthreads();  // prev iter's ds_reads done before overwrite
        *(uint4*)&As[sm][skc * 8] = va;
#pragma unroll
        for (int j = 0; j < 8; ++j) Bs[sng * 8 + j][sk] = e[j];
        __syncthreads();

#pragma unroll
        for (int am = 0; am < 2; ++am) {
            bf16x8 af = *(const bf16x8*)&As[wm * 32 + am * 16 + l15][kq * 8];
#pragma unroll
            for (int bn = 0; bn < 2; ++bn) {
                bf16x8 bfr = *(const bf16x8*)&Bs[wn * 32 + bn * 16 + l15][kq * 8];
                acc[am][bn] = __builtin_amdgcn_mfma_f32_16x16x32_bf16(af, bfr, acc[am][bn], 0, 0, 0);
            }
        }
    }

    // D layout: row = (lane>>4)*4 + reg, col = lane&15  [m89-verified]
#pragma unroll
    for (int am = 0; am < 2; ++am)
#pragma unroll
        for (int bn = 0; bn < 2; ++bn)
#pragma unroll
            for (int r = 0; r < 4; ++r) {
                int row = m0 + wm * 32 + am * 16 + kq * 4 + r;
                int col = n0 + wn * 32 + bn * 16 + l15;
                float v = acc[am][bn][r] + bias[col];
                if (RELU) v = fmaxf(v, 0.0f);
                if (OUTF32)
                    ((float*)Ov)[(size_t)row * N + col] = v;
                else
                    ((unsigned short*)Ov)[(size_t)row * N + col] = f2bf(v);
            }
}

// ---------------------------------------------------------------------------
// LayerNorm over D=256, all f32.  One wave per row, 4 rows/block.
// ---------------------------------------------------------------------------
__global__ __launch_bounds__(256) void ln_kernel(
    const float* __restrict__ Z, const float* __restrict__ g,
    const float* __restrict__ b, float* __restrict__ R)
{
    int row = blockIdx.x * 4 + (threadIdx.x >> 6);
    int lane = threadIdx.x & 63;
    float4 v = *(const float4*)(Z + (size_t)row * 256 + lane * 4);
    float s = v.x + v.y + v.z + v.w;
#pragma unroll
    for (int o = 32; o; o >>= 1) s += __shfl_xor(s, o);
    float mu = s * (1.0f / 256.0f);
    float4 d = {v.x - mu, v.y - mu, v.z - mu, v.w - mu};
    float q = d.x * d.x + d.y * d.y + d.z * d.z + d.w * d.w;
#pragma unroll
    for (int o = 32; o; o >>= 1) q += __shfl_xor(q, o);
    float var = q * (1.0f / 256.0f);
    float rs = 1.0f / sqrtf(var + 1e-5f);
    int c0 = lane * 4;
    float4 gg = *(const float4*)(g + c0);
    float4 bb = *(const float4*)(b + c0);
    float4 o4;
    o4.x = d.x * rs * gg.x + bb.x;
    o4.y = d.y * rs * gg.y + bb.y;
    o4.z = d.z * rs * gg.z + bb.z;
    o4.w = d.w * rs * gg.w + bb.w;
    *(float4*)(R + (size_t)row * 256 + c0) = o4;
}

// ---------------------------------------------------------------------------
// One residual-VQ stage, all f32.  Block = 256 threads, 16 rows x 1024 codes.
// d = (||r||^2 - 2 r.c) + ||c||^2 — same bracketing as the np reference.
// Argmin tie-break = lowest index via packed u64 min (matches np.argmin).
// idx written as float (f32 output buffer).
// ---------------------------------------------------------------------------
__global__ __launch_bounds__(256) void vq_stage(
    float* __restrict__ Rbuf, float* __restrict__ ZQ, float* __restrict__ LOSS,
    const float* __restrict__ CB, float* __restrict__ IDX,
    int stage)
{
    __shared__ float rs_[16][260];
    __shared__ unsigned long long red[16][257];
    __shared__ float rn_s[16];

    const int t = threadIdx.x;
    const int r0 = blockIdx.x * 16;

    {
        int row = t >> 4, j = t & 15;
#pragma unroll
        for (int q = 0; q < 4; ++q) {
            int col = j * 16 + q * 4;
            *(float4*)&rs_[row][col] =
                *(const float4*)(Rbuf + (size_t)(r0 + row) * 256 + col);
        }
    }
    __syncthreads();
    if (t < 16) {  // ||r||^2 sequential f32
        float s = 0.f;
        for (int d = 0; d < 256; ++d) s = fmaf(rs_[t][d], rs_[t][d], s);
        rn_s[t] = s;
    }
    __syncthreads();

    float bv[16];
    int bi[16];
#pragma unroll
    for (int r = 0; r < 16; ++r) { bv[r] = 3.4e38f; bi[r] = 0; }

    for (int cc = 0; cc < 4; ++cc) {
        int code = cc * 256 + t;  // ascending -> strict < keeps lowest index
        const float* crow = CB + (size_t)code * 256;
        float dot[16] = {};
        float cn = 0.f;
        for (int d8 = 0; d8 < 32; ++d8) {
            float4 c0 = *(const float4*)(crow + d8 * 8);
            float4 c1 = *(const float4*)(crow + d8 * 8 + 4);
            cn = fmaf(c0.x, c0.x, cn); cn = fmaf(c0.y, c0.y, cn);
            cn = fmaf(c0.z, c0.z, cn); cn = fmaf(c0.w, c0.w, cn);
            cn = fmaf(c1.x, c1.x, cn); cn = fmaf(c1.y, c1.y, cn);
            cn = fmaf(c1.z, c1.z, cn); cn = fmaf(c1.w, c1.w, cn);
#pragma unroll
            for (int row = 0; row < 16; ++row) {
                const float4* rp = (const float4*)&rs_[row][d8 * 8];
                float4 ra = rp[0], rb = rp[1];
                float a = dot[row];
                a = fmaf(ra.x, c0.x, a); a = fmaf(ra.y, c0.y, a);
                a = fmaf(ra.z, c0.z, a); a = fmaf(ra.w, c0.w, a);
                a = fmaf(rb.x, c1.x, a); a = fmaf(rb.y, c1.y, a);
                a = fmaf(rb.z, c1.z, a); a = fmaf(rb.w, c1.w, a);
                dot[row] = a;
            }
        }
#pragma unroll
        for (int row = 0; row < 16; ++row) {
            float dist = (rn_s[row] - 2.0f * dot[row]) + cn;
            if (dist < bv[row]) { bv[row] = dist; bi[row] = code; }
        }
    }

#pragma unroll
    for (int row = 0; row < 16; ++row)
        red[row][t] = (((unsigned long long)__builtin_bit_cast(unsigned int, bv[row])) << 32) |
                      (unsigned int)bi[row];
    __syncthreads();
    for (int off = 128; off; off >>= 1) {
        if (t < off) {
#pragma unroll
            for (int row = 0; row < 16; ++row) {
                unsigned long long a = red[row][t], b = red[row][t + off];
                if (b < a) red[row][t] = b;
            }
        }
        __syncthreads();
    }

    if (t < 16) {
        int row = t, grow = r0 + t;
        unsigned int idx = (unsigned int)(red[row][0] & 0xffffffffu);
        IDX[(size_t)grow * 3 + stage] = (float)idx;
        const float* e = CB + (size_t)idx * 256;
        float sum = 0.f;
        for (int d = 0; d < 256; ++d) {
            float ef = e[d];
            float diff = rs_[row][d] - ef;
            Rbuf[(size_t)grow * 256 + d] = diff;  // residual for next stage
            if (stage == 0) ZQ[(size_t)grow * 256 + d] = ef;
            else            ZQ[(size_t)grow * 256 + d] += ef;
            sum = fmaf(diff, diff, sum);
        }
        float m = sum * (1.0f / 256.0f);
        float l = m + BETA * m;  // sg() variants are value-equal
        if (stage == 0) LOSS[grow] = l;
        else            LOSS[grow] += l;
    }
}

// ---------------------------------------------------------------------------
// recon loss: mean((x_hat - x)^2) over 2048 (+ VQ losses), f32 out.
// ---------------------------------------------------------------------------
__global__ __launch_bounds__(256) void recon_kernel(
    const float* __restrict__ XH, const float* __restrict__ X,
    const float* __restrict__ LOSS_IN, float* __restrict__ LOSS_OUT)
{
    __shared__ float wsum[4];
    int row = blockIdx.x, t = threadIdx.x;
    float4 h0 = *(const float4*)(XH + (size_t)row * 2048 + t * 8);
    float4 h1 = *(const float4*)(XH + (size_t)row * 2048 + t * 8 + 4);
    float4 x0 = *(const float4*)(X + (size_t)row * 2048 + t * 8);
    float4 x1 = *(const float4*)(X + (size_t)row * 2048 + t * 8 + 4);
    float h[8] = {h0.x, h0.y, h0.z, h0.w, h1.x, h1.y, h1.z, h1.w};
    float xv[8] = {x0.x, x0.y, x0.z, x0.w, x1.x, x1.y, x1.z, x1.w};
    float s = 0.f;
#pragma unroll
    for (int j = 0; j < 8; ++j) {
        float d = h[j] - xv[j];
        s = fmaf(d, d, s);
    }
#pragma unroll
    for (int o = 32; o; o >>= 1) s += __shfl_xor(s, o);
    if ((t & 63) == 0) wsum[t >> 6] = s;
    __syncthreads();
    if (t == 0) {
        float tot = wsum[0] + wsum[1] + wsum[2] + wsum[3];
        LOSS_OUT[row] = LOSS_IN[row] + tot * (1.0f / 2048.0f);
    }
}

// ---------------------------------------------------------------------------
extern "C" void kernel_launch(void* const* d_in, const int* in_sizes, int n_in,
                              void* d_out, int out_size, void* d_ws, size_t ws_size,
                              hipStream_t stream)
{
    const float* x      = (const float*)d_in[0];
    const float* enc_W1 = (const float*)d_in[1];
    const float* enc_b1 = (const float*)d_in[2];
    const float* enc_W2 = (const float*)d_in[3];
    const float* enc_b2 = (const float*)d_in[4];
    const float* enc_W3 = (const float*)d_in[5];
    const float* enc_b3 = (const float*)d_in[6];
    const float* ln_g   = (const float*)d_in[7];
    const float* ln_b   = (const float*)d_in[8];
    const float* cb0    = (const float*)d_in[9];
    const float* cb1    = (const float*)d_in[10];
    const float* cb2    = (const float*)d_in[11];
    const float* dec_W1 = (const float*)d_in[12];
    const float* dec_b1 = (const float*)d_in[13];
    const float* dec_W2 = (const float*)d_in[14];
    const float* dec_b2 = (const float*)d_in[15];
    const float* dec_W3 = (const float*)d_in[16];
    const float* dec_b3 = (const float*)d_in[17];

    const int B = 16384, D_IN = 2048, H1 = 1024, H2 = 512, D_LAT = 256;

    // workspace overlays (128 MB + 64 KB total):
    //   [0,64M)    h1 f32   -> dead after enc GEMM2 -> d1 bf16 [0,16M),
    //                          d2 bf16 [16M,48M)
    //   [64,96M)   h2 f32   -> dead after enc GEMM3 -> lossf [64M,+64K)
    //   [96,112M)  z f32    -> dead after LN        -> zq f32
    //   [112,128M) r f32 (residual, live through VQ)
    char* ws = (char*)d_ws;
    float* h1    = (float*)(ws);
    float* h2    = (float*)(ws + (64u << 20));
    float* z     = (float*)(ws + (96u << 20));
    float* r     = (float*)(ws + (112u << 20));
    float* zq    = (float*)(ws + (96u << 20));
    float* lossf = (float*)(ws + (64u << 20));
    unsigned short* d1 = (unsigned short*)(ws);
    unsigned short* d2 = (unsigned short*)(ws + (16u << 20));

    // f32 output buffer: [x_hat 16384x2048 | loss 16384 | idx 16384x3]
    float* xhat     = (float*)d_out;
    float* loss_out = xhat + (size_t)B * D_IN;
    float* idx_out  = loss_out + B;

    // encoder (all f32 — argmin-critical)
    gemm_f32<true><<<dim3(H1 / 64, B / 64), 256, 0, stream>>>(
        x, enc_W1, enc_b1, h1, B, H1, D_IN);
    gemm_f32<true><<<dim3(H2 / 64, B / 64), 256, 0, stream>>>(
        h1, enc_W2, enc_b2, h2, B, H2, H1);
    gemm_f32<false><<<dim3(D_LAT / 64, B / 64), 256, 0, stream>>>(
        h2, enc_W3, enc_b3, z, B, D_LAT, H2);
    // layernorm
    ln_kernel<<<B / 4, 256, 0, stream>>>(z, ln_g, ln_b, r);
    // residual VQ (f32)
    vq_stage<<<B / 16, 256, 0, stream>>>(r, zq, lossf, cb0, idx_out, 0);
    vq_stage<<<B / 16, 256, 0, stream>>>(r, zq, lossf, cb1, idx_out, 1);
    vq_stage<<<B / 16, 256, 0, stream>>>(r, zq, lossf, cb2, idx_out, 2);
    // decoder (bf16 MFMA interior — 2% tolerance; final layer writes f32)
    gemm_mfma<true, true, false><<<dim3(H2 / 64, B / 64), 256, 0, stream>>>(
        zq, dec_W1, dec_b1, d1, B, H2, D_LAT);
    gemm_mfma<false, true, false><<<dim3(H1 / 64, B / 64), 256, 0, stream>>>(
        d1, dec_W2, dec_b2, d2, B, H1, H2);
    gemm_mfma<false, false, true><<<dim3(D_IN / 64, B / 64), 256, 0, stream>>>(
        d2, dec_W3, dec_b3, xhat, B, D_IN, H1);
    // losses
    recon_kernel<<<B, 256, 0, stream>>>(xhat, x, lossf, loss_out);
}

// Round 4
// 1812.275 us; speedup vs baseline: 1.6134x; 1.6134x over previous
//
#include <hip/hip_runtime.h>
#include <stdint.h>

typedef __bf16 bf16x8 __attribute__((ext_vector_type(8)));
typedef float f32x4 __attribute__((ext_vector_type(4)));

#define BETA 0.25f

__device__ __forceinline__ unsigned short f2bf(float f) {
    __bf16 h = (__bf16)f;
    return __builtin_bit_cast(unsigned short, h);
}

// ---------------------------------------------------------------------------
// 128x128 f32 VALU GEMM, 8x8 per thread.  Per-output fmaf chain is k-ascending
// -> bit-identical to round-3's 64x64 version (argmin-critical encoder path).
// ---------------------------------------------------------------------------
template <bool RELU>
__global__ __launch_bounds__(256) void gemm_f32_big(
    const float* __restrict__ A, const float* __restrict__ W,
    const float* __restrict__ bias, float* __restrict__ O,
    int M, int N, int K)
{
    __shared__ float As[16][132];   // [k][m]
    __shared__ float Bs[16][132];   // [k][n]

    const int t = threadIdx.x;
    const int m0 = blockIdx.y * 128, n0 = blockIdx.x * 128;
    const int tx = t & 15, ty = t >> 4;
    float c[8][8] = {};

    const int am_ = t >> 1, akc = (t & 1) * 8;   // A staging: row, k-chunk
    const int bk = t >> 4, bn8 = (t & 15) * 8;   // B staging: k-row, n-chunk

    for (int kb = 0; kb < K; kb += 16) {
        const float* ap = A + (size_t)(m0 + am_) * K + kb + akc;
        float4 a0 = *(const float4*)(ap);
        float4 a1 = *(const float4*)(ap + 4);
        const float* bp = W + (size_t)(kb + bk) * N + n0 + bn8;
        float4 b0 = *(const float4*)(bp);
        float4 b1 = *(const float4*)(bp + 4);

        __syncthreads();
        As[akc + 0][am_] = a0.x; As[akc + 1][am_] = a0.y;
        As[akc + 2][am_] = a0.z; As[akc + 3][am_] = a0.w;
        As[akc + 4][am_] = a1.x; As[akc + 5][am_] = a1.y;
        As[akc + 6][am_] = a1.z; As[akc + 7][am_] = a1.w;
        *(float4*)&Bs[bk][bn8] = b0;
        *(float4*)&Bs[bk][bn8 + 4] = b1;
        __syncthreads();

#pragma unroll
        for (int k = 0; k < 16; ++k) {
            float a[8], b[8];
            *(float4*)&a[0] = *(const float4*)&As[k][ty * 8];
            *(float4*)&a[4] = *(const float4*)&As[k][ty * 8 + 4];
            *(float4*)&b[0] = *(const float4*)&Bs[k][tx * 4];
            *(float4*)&b[4] = *(const float4*)&Bs[k][64 + tx * 4];
#pragma unroll
            for (int i = 0; i < 8; ++i)
#pragma unroll
                for (int j = 0; j < 8; ++j)
                    c[i][j] = fmaf(a[i], b[j], c[i][j]);
        }
    }

    float4 bv0 = *(const float4*)(bias + n0 + tx * 4);
    float4 bv1 = *(const float4*)(bias + n0 + 64 + tx * 4);
#pragma unroll
    for (int i = 0; i < 8; ++i) {
        int row = m0 + ty * 8 + i;
        float4 o0 = {c[i][0] + bv0.x, c[i][1] + bv0.y, c[i][2] + bv0.z, c[i][3] + bv0.w};
        float4 o1 = {c[i][4] + bv1.x, c[i][5] + bv1.y, c[i][6] + bv1.z, c[i][7] + bv1.w};
        if (RELU) {
            o0.x = fmaxf(o0.x, 0.f); o0.y = fmaxf(o0.y, 0.f);
            o0.z = fmaxf(o0.z, 0.f); o0.w = fmaxf(o0.w, 0.f);
            o1.x = fmaxf(o1.x, 0.f); o1.y = fmaxf(o1.y, 0.f);
            o1.z = fmaxf(o1.z, 0.f); o1.w = fmaxf(o1.w, 0.f);
        }
        *(float4*)(O + (size_t)row * N + n0 + tx * 4) = o0;
        *(float4*)(O + (size_t)row * N + n0 + 64 + tx * 4) = o1;
    }
}

// ---------------------------------------------------------------------------
// 64x64 f32 GEMM (round-3 proven) — encoder GEMM3 (N=256).
// ---------------------------------------------------------------------------
template <bool RELU>
__global__ __launch_bounds__(256) void gemm_f32(
    const float* __restrict__ A, const float* __restrict__ W,
    const float* __restrict__ bias, float* __restrict__ O,
    int M, int N, int K)
{
    __shared__ float Asf[16][68];
    __shared__ float Bsf[16][68];

    const int t = threadIdx.x;
    const int m0 = blockIdx.y * 64, n0 = blockIdx.x * 64;
    const int tx = t & 15, ty = t >> 4;
    float c[4][4] = {};

    const int sm = t >> 2, skc = t & 3;
    const int bk = t >> 4, bn4 = (t & 15) * 4;

    for (int kb = 0; kb < K; kb += 16) {
        float4 av = *(const float4*)(A + (size_t)(m0 + sm) * K + kb + skc * 4);
        float4 bw = *(const float4*)(W + (size_t)(kb + bk) * N + n0 + bn4);

        __syncthreads();
        Asf[skc * 4 + 0][sm] = av.x;
        Asf[skc * 4 + 1][sm] = av.y;
        Asf[skc * 4 + 2][sm] = av.z;
        Asf[skc * 4 + 3][sm] = av.w;
        *(float4*)&Bsf[bk][bn4] = bw;
        __syncthreads();

#pragma unroll
        for (int k = 0; k < 16; ++k) {
            float4 a = *(const float4*)&Asf[k][ty * 4];
            float4 b = *(const float4*)&Bsf[k][tx * 4];
            c[0][0] = fmaf(a.x, b.x, c[0][0]); c[0][1] = fmaf(a.x, b.y, c[0][1]);
            c[0][2] = fmaf(a.x, b.z, c[0][2]); c[0][3] = fmaf(a.x, b.w, c[0][3]);
            c[1][0] = fmaf(a.y, b.x, c[1][0]); c[1][1] = fmaf(a.y, b.y, c[1][1]);
            c[1][2] = fmaf(a.y, b.z, c[1][2]); c[1][3] = fmaf(a.y, b.w, c[1][3]);
            c[2][0] = fmaf(a.z, b.x, c[2][0]); c[2][1] = fmaf(a.z, b.y, c[2][1]);
            c[2][2] = fmaf(a.z, b.z, c[2][2]); c[2][3] = fmaf(a.z, b.w, c[2][3]);
            c[3][0] = fmaf(a.w, b.x, c[3][0]); c[3][1] = fmaf(a.w, b.y, c[3][1]);
            c[3][2] = fmaf(a.w, b.z, c[3][2]); c[3][3] = fmaf(a.w, b.w, c[3][3]);
        }
    }

    float4 bv = *(const float4*)(bias + n0 + tx * 4);
#pragma unroll
    for (int i = 0; i < 4; ++i) {
        int row = m0 + ty * 4 + i;
        float4 o;
        o.x = c[i][0] + bv.x; o.y = c[i][1] + bv.y;
        o.z = c[i][2] + bv.z; o.w = c[i][3] + bv.w;
        if (RELU) {
            o.x = fmaxf(o.x, 0.f); o.y = fmaxf(o.y, 0.f);
            o.z = fmaxf(o.z, 0.f); o.w = fmaxf(o.w, 0.f);
        }
        *(float4*)(O + (size_t)row * N + n0 + tx * 4) = o;
    }
}

// ---------------------------------------------------------------------------
// bf16 MFMA GEMM 64x64 (round-3 proven) — decoder layer 1 (f32 A/W).
// ---------------------------------------------------------------------------
template <bool AF32, bool RELU, bool OUTF32>
__global__ __launch_bounds__(256) void gemm_mfma(
    const void* __restrict__ Av, const float* __restrict__ W,
    const float* __restrict__ bias, void* __restrict__ Ov,
    int M, int N, int K)
{
    __shared__ unsigned short As[64][40];
    __shared__ unsigned short Bs[64][40];

    const int t = threadIdx.x;
    const int m0 = blockIdx.y * 64;
    const int n0 = blockIdx.x * 64;
    const int wave = t >> 6, lane = t & 63;
    const int wm = wave & 1, wn = wave >> 1;
    const int l15 = lane & 15, kq = lane >> 4;

    f32x4 acc[2][2] = {};

    const int sm = t >> 2, skc = t & 3;
    const int sk = t & 31, sng = t >> 5;

    for (int kb = 0; kb < K; kb += 32) {
        uint4 va;
        if (AF32) {
            const float* A = (const float*)Av;
            const float4* p = (const float4*)(A + (size_t)(m0 + sm) * K + kb + skc * 8);
            float4 a0 = p[0], a1 = p[1];
            va.x = (unsigned int)f2bf(a0.x) | ((unsigned int)f2bf(a0.y) << 16);
            va.y = (unsigned int)f2bf(a0.z) | ((unsigned int)f2bf(a0.w) << 16);
            va.z = (unsigned int)f2bf(a1.x) | ((unsigned int)f2bf(a1.y) << 16);
            va.w = (unsigned int)f2bf(a1.z) | ((unsigned int)f2bf(a1.w) << 16);
        } else {
            const unsigned short* A = (const unsigned short*)Av;
            va = *(const uint4*)(A + (size_t)(m0 + sm) * K + kb + skc * 8);
        }
        const float4* wp = (const float4*)(W + (size_t)(kb + sk) * N + n0 + sng * 8);
        float4 w0 = wp[0], w1 = wp[1];
        unsigned short e[8] = {f2bf(w0.x), f2bf(w0.y), f2bf(w0.z), f2bf(w0.w),
                               f2bf(w1.x), f2bf(w1.y), f2bf(w1.z), f2bf(w1.w)};

        __syncthreads();
        *(uint4*)&As[sm][skc * 8] = va;
#pragma unroll
        for (int j = 0; j < 8; ++j) Bs[sng * 8 + j][sk] = e[j];
        __syncthreads();

#pragma unroll
        for (int am = 0; am < 2; ++am) {
            bf16x8 af = *(const bf16x8*)&As[wm * 32 + am * 16 + l15][kq * 8];
#pragma unroll
            for (int bn = 0; bn < 2; ++bn) {
                bf16x8 bfr = *(const bf16x8*)&Bs[wn * 32 + bn * 16 + l15][kq * 8];
                acc[am][bn] = __builtin_amdgcn_mfma_f32_16x16x32_bf16(af, bfr, acc[am][bn], 0, 0, 0);
            }
        }
    }

#pragma unroll
    for (int am = 0; am < 2; ++am)
#pragma unroll
        for (int bn = 0; bn < 2; ++bn)
#pragma unroll
            for (int r = 0; r < 4; ++r) {
                int row = m0 + wm * 32 + am * 16 + kq * 4 + r;
                int col = n0 + wn * 32 + bn * 16 + l15;
                float v = acc[am][bn][r] + bias[col];
                if (RELU) v = fmaxf(v, 0.0f);
                if (OUTF32)
                    ((float*)Ov)[(size_t)row * N + col] = v;
                else
                    ((unsigned short*)Ov)[(size_t)row * N + col] = f2bf(v);
            }
}

// ---------------------------------------------------------------------------
// 128x128 bf16 MFMA GEMM, A[M,K] bf16, WT[N,K] bf16 (pre-transposed).
// 2x2 waves, each 64x64 via 4x4 of 16x16x32 MFMA.  Decoder layers 2/3.
// ---------------------------------------------------------------------------
template <bool RELU, bool OUTF32>
__global__ __launch_bounds__(256) void gemm_bt128(
    const unsigned short* __restrict__ A, const unsigned short* __restrict__ WT,
    const float* __restrict__ bias, void* __restrict__ Ov,
    int M, int N, int K)
{
    __shared__ unsigned short As[128][36];
    __shared__ unsigned short Bs[128][36];

    const int t = threadIdx.x;
    const int m0 = blockIdx.y * 128, n0 = blockIdx.x * 128;
    const int wave = t >> 6, lane = t & 63;
    const int wm = wave & 1, wn = wave >> 1;
    const int l15 = lane & 15, kq = lane >> 4;

    f32x4 acc[4][4] = {};

    const int sr = t >> 1, skc = (t & 1) * 16;

    for (int kb = 0; kb < K; kb += 32) {
        const unsigned short* ap = A + (size_t)(m0 + sr) * K + kb + skc;
        const unsigned short* bp = WT + (size_t)(n0 + sr) * K + kb + skc;
        uint4 va = *(const uint4*)(ap);
        uint4 va2 = *(const uint4*)(ap + 8);
        uint4 vb = *(const uint4*)(bp);
        uint4 vb2 = *(const uint4*)(bp + 8);

        __syncthreads();
        *(uint4*)&As[sr][skc] = va;
        *(uint4*)&As[sr][skc + 8] = va2;
        *(uint4*)&Bs[sr][skc] = vb;
        *(uint4*)&Bs[sr][skc + 8] = vb2;
        __syncthreads();

        bf16x8 bfr[4];
#pragma unroll
        for (int bn = 0; bn < 4; ++bn)
            bfr[bn] = *(const bf16x8*)&Bs[wn * 64 + bn * 16 + l15][kq * 8];
#pragma unroll
        for (int am = 0; am < 4; ++am) {
            bf16x8 af = *(const bf16x8*)&As[wm * 64 + am * 16 + l15][kq * 8];
#pragma unroll
            for (int bn = 0; bn < 4; ++bn)
                acc[am][bn] = __builtin_amdgcn_mfma_f32_16x16x32_bf16(af, bfr[bn], acc[am][bn], 0, 0, 0);
        }
    }

#pragma unroll
    for (int am = 0; am < 4; ++am)
#pragma unroll
        for (int bn = 0; bn < 4; ++bn)
#pragma unroll
            for (int r = 0; r < 4; ++r) {
                int row = m0 + wm * 64 + am * 16 + kq * 4 + r;
                int col = n0 + wn * 64 + bn * 16 + l15;
                float v = acc[am][bn][r] + bias[col];
                if (RELU) v = fmaxf(v, 0.0f);
                if (OUTF32)
                    ((float*)Ov)[(size_t)row * N + col] = v;
                else
                    ((unsigned short*)Ov)[(size_t)row * N + col] = f2bf(v);
            }
}

// ---------------------------------------------------------------------------
// Weight transpose + f32->bf16: W[K,N] f32 -> WT[N,K] bf16.
// ---------------------------------------------------------------------------
__global__ __launch_bounds__(256) void wtrans(
    const float* __restrict__ W, unsigned short* __restrict__ WT, int K, int N)
{
    __shared__ unsigned short tile[32][33];
    const int t = threadIdx.x;
    const int n0 = blockIdx.x * 32, k0 = blockIdx.y * 32;
    const int r = t >> 3, c4 = (t & 7) * 4;
    float4 w = *(const float4*)(W + (size_t)(k0 + r) * N + n0 + c4);
    tile[r][c4 + 0] = f2bf(w.x);
    tile[r][c4 + 1] = f2bf(w.y);
    tile[r][c4 + 2] = f2bf(w.z);
    tile[r][c4 + 3] = f2bf(w.w);
    __syncthreads();
    ushort4 o;
    o.x = tile[c4 + 0][r]; o.y = tile[c4 + 1][r];
    o.z = tile[c4 + 2][r]; o.w = tile[c4 + 3][r];
    *(ushort4*)(WT + (size_t)(n0 + r) * K + k0 + c4) = o;
}

// ---------------------------------------------------------------------------
// LayerNorm over D=256, f32.
// ---------------------------------------------------------------------------
__global__ __launch_bounds__(256) void ln_kernel(
    const float* __restrict__ Z, const float* __restrict__ g,
    const float* __restrict__ b, float* __restrict__ R)
{
    int row = blockIdx.x * 4 + (threadIdx.x >> 6);
    int lane = threadIdx.x & 63;
    float4 v = *(const float4*)(Z + (size_t)row * 256 + lane * 4);
    float s = v.x + v.y + v.z + v.w;
#pragma unroll
    for (int o = 32; o; o >>= 1) s += __shfl_xor(s, o);
    float mu = s * (1.0f / 256.0f);
    float4 d = {v.x - mu, v.y - mu, v.z - mu, v.w - mu};
    float q = d.x * d.x + d.y * d.y + d.z * d.z + d.w * d.w;
#pragma unroll
    for (int o = 32; o; o >>= 1) q += __shfl_xor(q, o);
    float var = q * (1.0f / 256.0f);
    float rs = 1.0f / sqrtf(var + 1e-5f);
    int c0 = lane * 4;
    float4 gg = *(const float4*)(g + c0);
    float4 bb = *(const float4*)(b + c0);
    float4 o4;
    o4.x = d.x * rs * gg.x + bb.x;
    o4.y = d.y * rs * gg.y + bb.y;
    o4.z = d.z * rs * gg.z + bb.z;
    o4.w = d.w * rs * gg.w + bb.w;
    *(float4*)(R + (size_t)row * 256 + c0) = o4;
}

// ---------------------------------------------------------------------------
// VQ: all f32 chains replicate round-3 fmaf order exactly (argmin-critical).
// ---------------------------------------------------------------------------
__global__ __launch_bounds__(256) void cninit_kernel(
    const float* __restrict__ CB, float* __restrict__ cn,
    unsigned long long* __restrict__ amin)
{
    int g = blockIdx.x * 256 + threadIdx.x;   // grid 64 -> 16384
    amin[g] = 0xFFFFFFFFFFFFFFFFULL;
    if (g < 1024) {
        const float* p = CB + (size_t)g * 256;
        float s = 0.f;
        for (int d = 0; d < 256; ++d) s = fmaf(p[d], p[d], s);
        cn[g] = s;
    }
}

__global__ __launch_bounds__(256) void rn_kernel(
    const float* __restrict__ R, float* __restrict__ rn)
{
    __shared__ float rs[16][260];
    const int t = threadIdx.x, r0 = blockIdx.x * 16;
    {
        int row = t >> 4, j = t & 15;
#pragma unroll
        for (int q = 0; q < 4; ++q) {
            int col = j * 16 + q * 4;
            *(float4*)&rs[row][col] = *(const float4*)(R + (size_t)(r0 + row) * 256 + col);
        }
    }
    __syncthreads();
    if (t < 16) {
        float s = 0.f;
        for (int d = 0; d < 256; ++d) s = fmaf(rs[t][d], rs[t][d], s);
        rn[r0 + t] = s;
    }
}

__global__ __launch_bounds__(256) void vq_dist(
    const float* __restrict__ Rbuf, const float* __restrict__ CB,
    const float* __restrict__ rn, const float* __restrict__ cn,
    unsigned long long* __restrict__ amin)
{
    __shared__ float As[16][132];   // [k][m]
    __shared__ float Bs[16][132];   // [k][code]
    __shared__ unsigned long long red[128][17];

    const int t = threadIdx.x;
    const int m0 = blockIdx.y * 128, n0 = blockIdx.x * 128;
    const int tx = t & 15, ty = t >> 4;
    float c[8][8] = {};

    const int sr = t >> 1, skc = (t & 1) * 8;

    for (int kb = 0; kb < 256; kb += 16) {
        const float* ap = Rbuf + (size_t)(m0 + sr) * 256 + kb + skc;
        float4 a0 = *(const float4*)(ap);
        float4 a1 = *(const float4*)(ap + 4);
        const float* bp = CB + (size_t)(n0 + sr) * 256 + kb + skc;
        float4 b0 = *(const float4*)(bp);
        float4 b1 = *(const float4*)(bp + 4);

        __syncthreads();
        As[skc + 0][sr] = a0.x; As[skc + 1][sr] = a0.y;
        As[skc + 2][sr] = a0.z; As[skc + 3][sr] = a0.w;
        As[skc + 4][sr] = a1.x; As[skc + 5][sr] = a1.y;
        As[skc + 6][sr] = a1.z; As[skc + 7][sr] = a1.w;
        Bs[skc + 0][sr] = b0.x; Bs[skc + 1][sr] = b0.y;
        Bs[skc + 2][sr] = b0.z; Bs[skc + 3][sr] = b0.w;
        Bs[skc + 4][sr] = b1.x; Bs[skc + 5][sr] = b1.y;
        Bs[skc + 6][sr] = b1.z; Bs[skc + 7][sr] = b1.w;
        __syncthreads();

#pragma unroll
        for (int k = 0; k < 16; ++k) {
            float a[8], b[8];
            *(float4*)&a[0] = *(const float4*)&As[k][ty * 8];
            *(float4*)&a[4] = *(const float4*)&As[k][ty * 8 + 4];
            *(float4*)&b[0] = *(const float4*)&Bs[k][tx * 4];
            *(float4*)&b[4] = *(const float4*)&Bs[k][64 + tx * 4];
#pragma unroll
            for (int i = 0; i < 8; ++i)
#pragma unroll
                for (int j = 0; j < 8; ++j)
                    c[i][j] = fmaf(a[i], b[j], c[i][j]);
        }
    }

    float rnv[8], cnv[8];
    *(float4*)&rnv[0] = *(const float4*)(rn + m0 + ty * 8);
    *(float4*)&rnv[4] = *(const float4*)(rn + m0 + ty * 8 + 4);
    *(float4*)&cnv[0] = *(const float4*)(cn + n0 + tx * 4);
    *(float4*)&cnv[4] = *(const float4*)(cn + n0 + 64 + tx * 4);

#pragma unroll
    for (int i = 0; i < 8; ++i) {
        unsigned long long best = 0xFFFFFFFFFFFFFFFFULL;
#pragma unroll
        for (int j = 0; j < 8; ++j) {
            float dist = (rnv[i] - 2.0f * c[i][j]) + cnv[j];
            int col = n0 + (j < 4 ? tx * 4 + j : 64 + tx * 4 + (j - 4));
            unsigned long long p =
                ((unsigned long long)__builtin_bit_cast(unsigned int, dist) << 32) |
                (unsigned int)col;
            if (p < best) best = p;
        }
        red[ty * 8 + i][tx] = best;
    }
    __syncthreads();
    if (t < 128) {
        unsigned long long b = red[t][0];
#pragma unroll
        for (int j = 1; j < 16; ++j) {
            unsigned long long v = red[t][j];
            if (v < b) b = v;
        }
        atomicMin(amin + m0 + t, b);
    }
}

__global__ __launch_bounds__(256) void vq_update(
    float* __restrict__ Rbuf, float* __restrict__ ZQ, float* __restrict__ lossf,
    const float* __restrict__ CB, const unsigned long long* __restrict__ amin,
    float* __restrict__ idx_out, int stage)
{
    __shared__ float lred[16][17];
    const int t = threadIdx.x, r0 = blockIdx.x * 16;
    const int row = r0 + (t >> 4), c16 = (t & 15) * 16;
    unsigned int idx = (unsigned int)(amin[row] & 0xffffffffu);
    const float* e = CB + (size_t)idx * 256 + c16;
    float* rp = Rbuf + (size_t)row * 256 + c16;
    float* zp = ZQ + (size_t)row * 256 + c16;
    float part = 0.f;
#pragma unroll
    for (int q = 0; q < 4; ++q) {
        float4 ev = *(const float4*)(e + q * 4);
        float4 rv = *(const float4*)(rp + q * 4);
        float4 dv = {rv.x - ev.x, rv.y - ev.y, rv.z - ev.z, rv.w - ev.w};
        *(float4*)(rp + q * 4) = dv;
        if (stage == 0) {
            *(float4*)(zp + q * 4) = ev;
        } else {
            float4 zv = *(const float4*)(zp + q * 4);
            zv.x += ev.x; zv.y += ev.y; zv.z += ev.z; zv.w += ev.w;
            *(float4*)(zp + q * 4) = zv;
        }
        part = fmaf(dv.x, dv.x, part);
        part = fmaf(dv.y, dv.y, part);
        part = fmaf(dv.z, dv.z, part);
        part = fmaf(dv.w, dv.w, part);
    }
    lred[t >> 4][t & 15] = part;
    __syncthreads();
    if (t < 16) {
        float s = 0.f;
        for (int j = 0; j < 16; ++j) s += lred[t][j];
        float m = s * (1.0f / 256.0f);
        float l = m + BETA * m;
        int gr = r0 + t;
        if (stage == 0) lossf[gr] = l;
        else            lossf[gr] += l;
        idx_out[(size_t)gr * 3 + stage] =
            (float)(unsigned int)(amin[gr] & 0xffffffffu);
    }
}

// ---------------------------------------------------------------------------
// recon loss.
// ---------------------------------------------------------------------------
__global__ __launch_bounds__(256) void recon_kernel(
    const float* __restrict__ XH, const float* __restrict__ X,
    const float* __restrict__ LOSS_IN, float* __restrict__ LOSS_OUT)
{
    __shared__ float wsum[4];
    int row = blockIdx.x, t = threadIdx.x;
    float4 h0 = *(const float4*)(XH + (size_t)row * 2048 + t * 8);
    float4 h1 = *(const float4*)(XH + (size_t)row * 2048 + t * 8 + 4);
    float4 x0 = *(const float4*)(X + (size_t)row * 2048 + t * 8);
    float4 x1 = *(const float4*)(X + (size_t)row * 2048 + t * 8 + 4);
    float h[8] = {h0.x, h0.y, h0.z, h0.w, h1.x, h1.y, h1.z, h1.w};
    float xv[8] = {x0.x, x0.y, x0.z, x0.w, x1.x, x1.y, x1.z, x1.w};
    float s = 0.f;
#pragma unroll
    for (int j = 0; j < 8; ++j) {
        float d = h[j] - xv[j];
        s = fmaf(d, d, s);
    }
#pragma unroll
    for (int o = 32; o; o >>= 1) s += __shfl_xor(s, o);
    if ((t & 63) == 0) wsum[t >> 6] = s;
    __syncthreads();
    if (t == 0) {
        float tot = wsum[0] + wsum[1] + wsum[2] + wsum[3];
        LOSS_OUT[row] = LOSS_IN[row] + tot * (1.0f / 2048.0f);
    }
}

// ---------------------------------------------------------------------------
extern "C" void kernel_launch(void* const* d_in, const int* in_sizes, int n_in,
                              void* d_out, int out_size, void* d_ws, size_t ws_size,
                              hipStream_t stream)
{
    const float* x      = (const float*)d_in[0];
    const float* enc_W1 = (const float*)d_in[1];
    const float* enc_b1 = (const float*)d_in[2];
    const float* enc_W2 = (const float*)d_in[3];
    const float* enc_b2 = (const float*)d_in[4];
    const float* enc_W3 = (const float*)d_in[5];
    const float* enc_b3 = (const float*)d_in[6];
    const float* ln_g   = (const float*)d_in[7];
    const float* ln_b   = (const float*)d_in[8];
    const float* cb0    = (const float*)d_in[9];
    const float* cb1    = (const float*)d_in[10];
    const float* cb2    = (const float*)d_in[11];
    const float* dec_W1 = (const float*)d_in[12];
    const float* dec_b1 = (const float*)d_in[13];
    const float* dec_W2 = (const float*)d_in[14];
    const float* dec_b2 = (const float*)d_in[15];
    const float* dec_W3 = (const float*)d_in[16];
    const float* dec_b3 = (const float*)d_in[17];

    const int B = 16384, D_IN = 2048, H1 = 1024, H2 = 512, D_LAT = 256;

    // workspace overlays (<= 128 MB):
    //   [0,64M)   h1 f32; dead after enc G2 -> d1 [0,16M), d2 [16M,48M),
    //             WT3 [48M,52M), WT2 [52M,53M)
    //   [64,96M)  h2 f32; dead after enc G3 -> lossf 64M, cn 65M, amin 66M, rn 67M
    //   [96,112M) z f32;  dead after LN -> zq f32
    //   [112,128M) r f32 (residual, live through VQ)
    char* ws = (char*)d_ws;
    float* h1    = (float*)(ws);
    float* h2    = (float*)(ws + (64u << 20));
    float* z     = (float*)(ws + (96u << 20));
    float* r     = (float*)(ws + (112u << 20));
    float* zq    = (float*)(ws + (96u << 20));
    unsigned short* d1  = (unsigned short*)(ws);
    unsigned short* d2  = (unsigned short*)(ws + (16u << 20));
    unsigned short* wt3 = (unsigned short*)(ws + (48u << 20));
    unsigned short* wt2 = (unsigned short*)(ws + (52u << 20));
    float* lossf = (float*)(ws + (64u << 20));
    float* cn    = (float*)(ws + (65u << 20));
    unsigned long long* amin = (unsigned long long*)(ws + (66u << 20));
    float* rnb   = (float*)(ws + (67u << 20));

    float* xhat     = (float*)d_out;
    float* loss_out = xhat + (size_t)B * D_IN;
    float* idx_out  = loss_out + B;

    // encoder (f32, argmin-critical)
    gemm_f32_big<true><<<dim3(H1 / 128, B / 128), 256, 0, stream>>>(
        x, enc_W1, enc_b1, h1, B, H1, D_IN);
    gemm_f32_big<true><<<dim3(H2 / 128, B / 128), 256, 0, stream>>>(
        h1, enc_W2, enc_b2, h2, B, H2, H1);
    // decoder weight prep (h1 dead now)
    wtrans<<<dim3(H1 / 32, H2 / 32), 256, 0, stream>>>(dec_W2, wt2, H2, H1);
    wtrans<<<dim3(D_IN / 32, H1 / 32), 256, 0, stream>>>(dec_W3, wt3, H1, D_IN);
    gemm_f32<false><<<dim3(D_LAT / 64, B / 64), 256, 0, stream>>>(
        h2, enc_W3, enc_b3, z, B, D_LAT, H2);
    ln_kernel<<<B / 4, 256, 0, stream>>>(z, ln_g, ln_b, r);

    // residual VQ
    const float* cbs[3] = {cb0, cb1, cb2};
    for (int s = 0; s < 3; ++s) {
        cninit_kernel<<<64, 256, 0, stream>>>(cbs[s], cn, amin);
        rn_kernel<<<B / 16, 256, 0, stream>>>(r, rnb);
        vq_dist<<<dim3(1024 / 128, B / 128), 256, 0, stream>>>(r, cbs[s], rnb, cn, amin);
        vq_update<<<B / 16, 256, 0, stream>>>(r, zq, lossf, cbs[s], amin, idx_out, s);
    }

    // decoder
    gemm_mfma<true, true, false><<<dim3(H2 / 64, B / 64), 256, 0, stream>>>(
        zq, dec_W1, dec_b1, d1, B, H2, D_LAT);
    gemm_bt128<true, false><<<dim3(H1 / 128, B / 128), 256, 0, stream>>>(
        d1, wt2, dec_b2, d2, B, H1, H2);
    gemm_bt128<false, true><<<dim3(D_IN / 128, B / 128), 256, 0, stream>>>(
        d2, wt3, dec_b3, xhat, B, D_IN, H1);
    recon_kernel<<<B, 256, 0, stream>>>(xhat, x, lossf, loss_out);
}